// Round 8
// baseline (180.576 us; speedup 1.0000x reference)
//
#include <hip/hip_runtime.h>
#include <hip/hip_bf16.h>

// B=4, C=128, H=W=64 -> N=4096. ALL I/O FP32.
// Round 8: proj register-blocked 8 outputs/thread (hides L2 latency behind
// 24 FMAs per load; contiguous ushort8 q/k stores). Flash unchanged from the
// measured-good R5/R7 config. Partials Op stored bf16 (halves write+combine
// traffic). DO NOT tighten __launch_bounds__ on flash: (256,3) forced
// VGPR 124->84 -> scratch spill (FETCH 35->192 MB, 58->150us) in Round 6.

#define BATCH 4
#define CH    128
#define NTOK  4096
#define TK    64
#define SCALE 0.08838834764831845f   // 1/sqrt(128)
#define LOG2E 1.4426950408889634f
#define MFIX  16.0f                  // fixed softmax offset (log2 units)
#define PSTR  72                     // P scratch row stride (ushort)

typedef __attribute__((ext_vector_type(8)))  short short8;
typedef __attribute__((ext_vector_type(16))) float f32x16;

static __device__ __forceinline__ unsigned short f2bf(float f) {
    __hip_bfloat16 h = (__hip_bfloat16)f;
    return *(const unsigned short*)&h;
}
static __device__ __forceinline__ float bf2f(unsigned short u) {
    const unsigned int v = ((unsigned int)u) << 16;
    return *(const float*)&v;
}

// ---------------- VALU QKV projection (8 outputs/thread) ----------------
// grid (NTOK/256, CH/8, BATCH) = 1024 blocks, 256 thr.
// x coalesced along n (1 load per 24 FMAs); W rows wave-uniform (s_load).
__global__ __launch_bounds__(256) void proj_valu_kernel(
    const float* __restrict__ x,
    const float* __restrict__ Wq, const float* __restrict__ bq,
    const float* __restrict__ Wk, const float* __restrict__ bk,
    const float* __restrict__ Wv, const float* __restrict__ bv,
    unsigned short* __restrict__ q_ws,
    unsigned short* __restrict__ k_ws,
    unsigned short* __restrict__ vt_ws)
{
    const int n  = blockIdx.x * 256 + threadIdx.x;
    const int d0 = blockIdx.y * 8;
    const int b  = blockIdx.z;
    const float* xb = x + (size_t)b * CH * NTOK;

    float aq[8], ak[8], av[8];
    #pragma unroll
    for (int i = 0; i < 8; ++i) {
        aq[i] = bq[d0 + i];
        ak[i] = bk[d0 + i];
        av[i] = bv[d0 + i];
    }

    #pragma unroll 8
    for (int c = 0; c < CH; ++c) {
        const float xv = xb[(size_t)c * NTOK + n];
        #pragma unroll
        for (int i = 0; i < 8; ++i) {
            aq[i] = fmaf(Wq[(d0 + i) * CH + c], xv, aq[i]);
            ak[i] = fmaf(Wk[(d0 + i) * CH + c], xv, ak[i]);
            av[i] = fmaf(Wv[(d0 + i) * CH + c], xv, av[i]);
        }
    }

    unsigned short qv[8], kv[8];
    #pragma unroll
    for (int i = 0; i < 8; ++i) {
        qv[i] = f2bf(aq[i] * (SCALE * LOG2E));   // log2-domain scores
        kv[i] = f2bf(ak[i]);
    }
    const size_t o = ((size_t)b * NTOK + n) * CH + d0;
    *(short8*)(q_ws + o) = *(const short8*)qv;   // 16 B contiguous per thread
    *(short8*)(k_ws + o) = *(const short8*)kv;
    #pragma unroll
    for (int i = 0; i < 8; ++i)                  // coalesced along n per d
        vt_ws[((size_t)b * CH + d0 + i) * NTOK + n] = f2bf(av[i]);
}

// ---------------- split-KV MFMA flash attention (fixed-m, 32x32 tiles) ------
// block = 256 thr = 4 waves x 32 Q-rows = 128 rows. grid (32, SPLIT, B).
template <int SPLIT>
__global__ __launch_bounds__(256, 2) void flash_attn_mfma(
    const unsigned short* __restrict__ q_ws,
    const unsigned short* __restrict__ k_ws,
    const unsigned short* __restrict__ vt_ws,
    float* __restrict__ out,
    unsigned short* __restrict__ Op, float* __restrict__ l_p)
{
    __shared__ __align__(16) unsigned short KsU[TK * CH];        // 16 KB
    __shared__ __align__(16) unsigned short VtU[CH * TK];        // 16 KB
    __shared__ __align__(16) unsigned short PlU[4 * 32 * PSTR];  // 18 KB

    const int t    = threadIdx.x;
    const int w    = t >> 6;
    const int lane = t & 63;
    const int half = lane >> 5;
    const int l32  = lane & 31;
    const int jc   = blockIdx.y;
    const int b    = blockIdx.z;
    const int n0   = blockIdx.x * 128;
    const int jbeg = jc * (NTOK / SPLIT);
    const int jend = jbeg + (NTOK / SPLIT);

    // Q A-frags: wave rows n0+32w .. +31. A[m=l32][k=16ks+8half+j]
    short8 qa[8];
    {
        const unsigned short* qrow = q_ws + ((size_t)b * NTOK + n0 + 32 * w + l32) * CH;
        #pragma unroll
        for (int ks = 0; ks < 8; ++ks)
            qa[ks] = *(const short8*)(qrow + ks * 16 + half * 8);
    }

    f32x16 Oa[4];
    #pragma unroll
    for (int ct = 0; ct < 4; ++ct) Oa[ct] = (f32x16)(0.0f);
    f32x16 La = (f32x16)(0.0f);

    const unsigned short* kg = k_ws  + (size_t)b * NTOK * CH;
    const unsigned short* vg = vt_ws + (size_t)b * CH * NTOK;
    const short8 ones8 = (short8)(short)0x3F80;  // bf16 1.0 x8
    unsigned short* Pw = &PlU[w * 32 * PSTR];

    for (int j0 = jbeg; j0 < jend; j0 += TK) {
        __syncthreads();

        {   // stage K rows 16w..16w+15 (XOR-swizzled source, lane-contig dest)
            const int rl = lane >> 4, u = lane & 15;
            #pragma unroll
            for (int ci = 0; ci < 4; ++ci) {
                const int row = 16 * w + 4 * ci + rl;
                const int g   = u ^ (row & 15);
                const unsigned short* src = kg + (size_t)(j0 + row) * CH + g * 8;
                __builtin_amdgcn_global_load_lds(
                    (const __attribute__((address_space(1))) void*)src,
                    (__attribute__((address_space(3))) void*)&KsU[(16 * w + 4 * ci) * CH],
                    16, 0, 0);
            }
        }
        {   // stage V^T channel rows 32w..32w+31
            const int cl = lane >> 3, u = lane & 7;
            #pragma unroll
            for (int ci = 0; ci < 4; ++ci) {
                const int c = 32 * w + 8 * ci + cl;
                const int g = u ^ (c & 7);
                const unsigned short* src = vg + (size_t)c * NTOK + j0 + g * 8;
                __builtin_amdgcn_global_load_lds(
                    (const __attribute__((address_space(1))) void*)src,
                    (__attribute__((address_space(3))) void*)&VtU[(32 * w + 8 * ci) * TK],
                    16, 0, 0);
            }
        }
        __syncthreads();

        // --- S = Q K^T - MFIX : two 32x32 token tiles, 8 k-steps each ---
        f32x16 s0 = (f32x16)(-MFIX);
        f32x16 s1 = (f32x16)(-MFIX);
        #pragma unroll
        for (int ks = 0; ks < 8; ++ks) {
            const int ph = (2 * ks + half) ^ (l32 & 15);
            const short8 kf0 = *(const short8*)&KsU[l32 * CH + ph * 8];
            const short8 kf1 = *(const short8*)&KsU[(32 + l32) * CH + ph * 8];
            s0 = __builtin_amdgcn_mfma_f32_32x32x16_bf16(qa[ks], kf0, s0, 0, 0, 0);
            s1 = __builtin_amdgcn_mfma_f32_32x32x16_bf16(qa[ks], kf1, s1, 0, 0, 0);
        }

        // --- P = exp2(S) (m fixed) -> per-wave LDS scratch, row-major ---
        #pragma unroll
        for (int reg = 0; reg < 16; ++reg) {
            const int row = (reg & 3) + 8 * (reg >> 2) + 4 * half;
            Pw[row * PSTR + l32]      = f2bf(exp2f(s0[reg]));
            Pw[row * PSTR + 32 + l32] = f2bf(exp2f(s1[reg]));
        }
        __threadfence_block();

        // --- O += P V ; l += P * ones (no rescale: m is fixed) ---
        #pragma unroll
        for (int ks2 = 0; ks2 < 4; ++ks2) {
            const short8 pa = *(const short8*)&Pw[l32 * PSTR + ks2 * 16 + half * 8];
            #pragma unroll
            for (int ct = 0; ct < 4; ++ct) {
                const int ch = ct * 32 + l32;
                const int ph = (2 * ks2 + half) ^ (ch & 7);
                const short8 vf = *(const short8*)&VtU[ch * TK + ph * 8];
                Oa[ct] = __builtin_amdgcn_mfma_f32_32x32x16_bf16(pa, vf, Oa[ct], 0, 0, 0);
            }
            La = __builtin_amdgcn_mfma_f32_32x32x16_bf16(pa, ones8, La, 0, 0, 0);
        }
    }

    if constexpr (SPLIT == 1) {
        #pragma unroll
        for (int reg = 0; reg < 16; ++reg) {
            const int row = (reg & 3) + 8 * (reg >> 2) + 4 * half;
            const int n = n0 + 32 * w + row;
            const float inv = 1.0f / La[reg];
            #pragma unroll
            for (int ct = 0; ct < 4; ++ct)
                out[((size_t)b * CH + ct * 32 + l32) * NTOK + n] = Oa[ct][reg] * inv;
        }
    } else {
        const size_t chunk = (size_t)(b * SPLIT + jc);
        #pragma unroll
        for (int reg = 0; reg < 16; ++reg) {
            const int row = (reg & 3) + 8 * (reg >> 2) + 4 * half;
            const int n = n0 + 32 * w + row;
            const size_t base = (chunk * NTOK + n) * CH;
            #pragma unroll
            for (int ct = 0; ct < 4; ++ct)   // lanes 0-31 / 32-63: 64 B segments
                Op[base + ct * 32 + l32] = f2bf(Oa[ct][reg]);
            if (l32 == 0) l_p[chunk * NTOK + n] = La[reg];
        }
    }
}

// ---------------- combine partials (plain sums; fixed m) ----------------
template <int SPLIT>
__global__ __launch_bounds__(256) void combine_kernel(
    const unsigned short* __restrict__ Op, const float* __restrict__ l_p,
    float* __restrict__ out)
{
    const int t  = threadIdx.x;
    const int cg = t & 31;
    const int r8 = t >> 5;
    const int n0 = blockIdx.x * 32;
    const int b  = blockIdx.y;

    for (int it = 0; it < 4; ++it) {
        const int n = n0 + it * 8 + r8;
        float den = 0.f;
        float acc[4] = {0.f, 0.f, 0.f, 0.f};
        #pragma unroll
        for (int j = 0; j < SPLIT; ++j) {
            const size_t chunk = (size_t)(b * SPLIT + j);
            den += l_p[chunk * NTOK + n];
            unsigned short o4[4];
            *(uint2*)o4 = *(const uint2*)&Op[(chunk * NTOK + n) * CH + cg * 4];
            #pragma unroll
            for (int e = 0; e < 4; ++e) acc[e] += bf2f(o4[e]);
        }
        const float inv = 1.0f / den;
        #pragma unroll
        for (int e = 0; e < 4; ++e)
            out[((size_t)b * CH + cg * 4 + e) * NTOK + n] = acc[e] * inv;
    }
}

extern "C" void kernel_launch(void* const* d_in, const int* in_sizes, int n_in,
                              void* d_out, int out_size, void* d_ws, size_t ws_size,
                              hipStream_t stream) {
    const float* x  = (const float*)d_in[0];
    const float* Wq = (const float*)d_in[1];
    const float* bq = (const float*)d_in[2];
    const float* Wk = (const float*)d_in[3];
    const float* bk = (const float*)d_in[4];
    const float* Wv = (const float*)d_in[5];
    const float* bv = (const float*)d_in[6];
    float* out = (float*)d_out;

    const size_t QKV = (size_t)BATCH * NTOK * CH;
    unsigned short* q_ws  = (unsigned short*)d_ws;
    unsigned short* k_ws  = q_ws + QKV;
    unsigned short* vt_ws = k_ws + QKV;
    unsigned short* Op    = vt_ws + QKV;   // bf16 partials [S*B][N][C]

    const size_t baseBytes = 3 * QKV * 2;
    auto needBytes = [&](size_t S) {
        return baseBytes + S * BATCH * NTOK * (size_t)(CH * 2 + 4);
    };

    dim3 gp(NTOK / 256, CH / 8, BATCH);
    proj_valu_kernel<<<gp, 256, 0, stream>>>(x, Wq, bq, Wk, bk, Wv, bv,
                                             q_ws, k_ws, vt_ws);

    if (ws_size >= needBytes(8)) {
        float* l_p = (float*)(Op + (size_t)8 * BATCH * NTOK * CH);
        dim3 ga(NTOK / 128, 8, BATCH);
        flash_attn_mfma<8><<<ga, 256, 0, stream>>>(q_ws, k_ws, vt_ws, out, Op, l_p);
        dim3 gc(NTOK / 32, BATCH);
        combine_kernel<8><<<gc, 256, 0, stream>>>(Op, l_p, out);
    } else if (ws_size >= needBytes(4)) {
        float* l_p = (float*)(Op + (size_t)4 * BATCH * NTOK * CH);
        dim3 ga(NTOK / 128, 4, BATCH);
        flash_attn_mfma<4><<<ga, 256, 0, stream>>>(q_ws, k_ws, vt_ws, out, Op, l_p);
        dim3 gc(NTOK / 32, BATCH);
        combine_kernel<4><<<gc, 256, 0, stream>>>(Op, l_p, out);
    } else {
        dim3 ga(NTOK / 128, 1, BATCH);
        flash_attn_mfma<1><<<ga, 256, 0, stream>>>(q_ws, k_ws, vt_ws, out,
                                                   nullptr, nullptr);
    }
}

// Round 9
// 164.119 us; speedup vs baseline: 1.1003x; 1.1003x over previous
//
#include <hip/hip_runtime.h>
#include <hip/hip_bf16.h>

// B=4, C=128, H=W=64 -> N=4096. ALL I/O FP32.
// Round 9: flash is STAGING-BW bound (R4:512MB->106us, R5:268MB->58us, ~4.6TB/s).
//  - Q-tile 256 rows (512 thr, 8 waves): staging 268->134 MB.
//  - XCD swizzle: 16 sharer-blocks of each K/V chunk -> one XCD (L2 reuse).
//  - proj: 4 outputs/thread, unroll 4 -> W loads stay SCALAR (R8's unroll-8
//    x 24 values overflowed SGPRs -> vector-load flood, 60us).
// DO NOT tighten flash __launch_bounds__: R6's (256,3) caused VGPR 124->84
// scratch spill (FETCH 35->192MB, 58->150us).

#define BATCH 4
#define CH    128
#define NTOK  4096
#define TK    64
#define QTILE 256
#define SCALE 0.08838834764831845f   // 1/sqrt(128)
#define LOG2E 1.4426950408889634f
#define MFIX  16.0f                  // fixed softmax offset (log2 units)
#define PSTR  72                     // P scratch row stride (ushort)

typedef __attribute__((ext_vector_type(8)))  short short8;
typedef __attribute__((ext_vector_type(16))) float f32x16;

static __device__ __forceinline__ unsigned short f2bf(float f) {
    __hip_bfloat16 h = (__hip_bfloat16)f;
    return *(const unsigned short*)&h;
}
static __device__ __forceinline__ float bf2f(unsigned short u) {
    const unsigned int v = ((unsigned int)u) << 16;
    return *(const float*)&v;
}

// ---------------- VALU QKV projection (4 outputs/thread) ----------------
// grid (NTOK/256, CH/4, BATCH) = 2048 blocks, 256 thr. 48 scalar W values
// per unroll-4 chunk (fits SGPRs -> s_load, zero VALU cost).
__global__ __launch_bounds__(256) void proj_valu_kernel(
    const float* __restrict__ x,
    const float* __restrict__ Wq, const float* __restrict__ bq,
    const float* __restrict__ Wk, const float* __restrict__ bk,
    const float* __restrict__ Wv, const float* __restrict__ bv,
    unsigned short* __restrict__ q_ws,
    unsigned short* __restrict__ k_ws,
    unsigned short* __restrict__ vt_ws)
{
    const int n  = blockIdx.x * 256 + threadIdx.x;
    const int d0 = blockIdx.y * 4;
    const int b  = blockIdx.z;
    const float* xb = x + (size_t)b * CH * NTOK;

    float aq[4], ak[4], av[4];
    #pragma unroll
    for (int i = 0; i < 4; ++i) {
        aq[i] = bq[d0 + i];
        ak[i] = bk[d0 + i];
        av[i] = bv[d0 + i];
    }

    #pragma unroll 4
    for (int c = 0; c < CH; ++c) {
        const float xv = xb[(size_t)c * NTOK + n];
        #pragma unroll
        for (int i = 0; i < 4; ++i) {
            aq[i] = fmaf(Wq[(d0 + i) * CH + c], xv, aq[i]);
            ak[i] = fmaf(Wk[(d0 + i) * CH + c], xv, ak[i]);
            av[i] = fmaf(Wv[(d0 + i) * CH + c], xv, av[i]);
        }
    }

    unsigned short qv[4], kv[4];
    #pragma unroll
    for (int i = 0; i < 4; ++i) {
        qv[i] = f2bf(aq[i] * (SCALE * LOG2E));   // log2-domain scores
        kv[i] = f2bf(ak[i]);
    }
    const size_t o = ((size_t)b * NTOK + n) * CH + d0;
    *(uint2*)(q_ws + o) = *(const uint2*)qv;     // 8 B contiguous per thread
    *(uint2*)(k_ws + o) = *(const uint2*)kv;
    #pragma unroll
    for (int i = 0; i < 4; ++i)                  // coalesced along n per d
        vt_ws[((size_t)b * CH + d0 + i) * NTOK + n] = f2bf(av[i]);
}

// ---------------- split-KV MFMA flash attention (fixed-m, 32x32 tiles) ------
// 512 thr = 8 waves x 32 Q-rows = 256 rows/block. SPLIT=8: flat grid of 512,
// decoded so all 16 sharers of a (jc,b) K/V chunk land on one XCD (id&7).
template <int SPLIT>
__global__ __launch_bounds__(512, 2) void flash_attn_mfma(
    const unsigned short* __restrict__ q_ws,
    const unsigned short* __restrict__ k_ws,
    const unsigned short* __restrict__ vt_ws,
    float* __restrict__ out,
    unsigned short* __restrict__ Op, float* __restrict__ l_p)
{
    __shared__ __align__(16) unsigned short KsU[TK * CH];        // 16 KB
    __shared__ __align__(16) unsigned short VtU[CH * TK];        // 16 KB
    __shared__ __align__(16) unsigned short PlU[8 * 32 * PSTR];  // 36 KB

    const int t    = threadIdx.x;
    const int w    = t >> 6;          // 0..7
    const int lane = t & 63;
    const int half = lane >> 5;
    const int l32  = lane & 31;

    int tile, jc, b;
    if constexpr (SPLIT == 8) {
        // id&7 = XCD (round-robin dispatch assumption; perf-only heuristic).
        const int id   = blockIdx.x;        // 0..511
        const int xcd  = id & 7;
        const int slot = id >> 3;           // 0..63
        const int chunk = xcd * 4 + (slot >> 4);   // 0..31: 4 chunks per XCD
        tile = slot & 15;
        jc   = chunk & 7;
        b    = chunk >> 3;
    } else {
        tile = blockIdx.x; jc = blockIdx.y; b = blockIdx.z;
    }
    const int n0   = tile * QTILE;
    const int jbeg = jc * (NTOK / SPLIT);
    const int jend = jbeg + (NTOK / SPLIT);

    // Q A-frags: wave rows n0+32w .. +31. A[m=l32][k=16ks+8half+j]
    short8 qa[8];
    {
        const unsigned short* qrow = q_ws + ((size_t)b * NTOK + n0 + 32 * w + l32) * CH;
        #pragma unroll
        for (int ks = 0; ks < 8; ++ks)
            qa[ks] = *(const short8*)(qrow + ks * 16 + half * 8);
    }

    f32x16 Oa[4];
    #pragma unroll
    for (int ct = 0; ct < 4; ++ct) Oa[ct] = (f32x16)(0.0f);
    f32x16 La = (f32x16)(0.0f);

    const unsigned short* kg = k_ws  + (size_t)b * NTOK * CH;
    const unsigned short* vg = vt_ws + (size_t)b * CH * NTOK;
    const short8 ones8 = (short8)(short)0x3F80;  // bf16 1.0 x8
    unsigned short* Pw = &PlU[w * 32 * PSTR];

    for (int j0 = jbeg; j0 < jend; j0 += TK) {
        __syncthreads();

        {   // stage K: wave w rows 8w..8w+7 (XOR-swizzled source, lane-contig dest)
            const int rl = lane >> 4, u = lane & 15;
            #pragma unroll
            for (int ci = 0; ci < 2; ++ci) {
                const int row = 8 * w + 4 * ci + rl;
                const int g   = u ^ (row & 15);
                const unsigned short* src = kg + (size_t)(j0 + row) * CH + g * 8;
                __builtin_amdgcn_global_load_lds(
                    (const __attribute__((address_space(1))) void*)src,
                    (__attribute__((address_space(3))) void*)&KsU[(8 * w + 4 * ci) * CH],
                    16, 0, 0);
            }
        }
        {   // stage V^T: wave w channel rows 16w..16w+15
            const int cl = lane >> 3, u = lane & 7;
            #pragma unroll
            for (int ci = 0; ci < 2; ++ci) {
                const int c = 16 * w + 8 * ci + cl;
                const int g = u ^ (c & 7);
                const unsigned short* src = vg + (size_t)c * NTOK + j0 + g * 8;
                __builtin_amdgcn_global_load_lds(
                    (const __attribute__((address_space(1))) void*)src,
                    (__attribute__((address_space(3))) void*)&VtU[(16 * w + 8 * ci) * TK],
                    16, 0, 0);
            }
        }
        __syncthreads();

        // --- S = Q K^T - MFIX : two 32x32 token tiles, 8 k-steps each ---
        f32x16 s0 = (f32x16)(-MFIX);
        f32x16 s1 = (f32x16)(-MFIX);
        #pragma unroll
        for (int ks = 0; ks < 8; ++ks) {
            const int ph = (2 * ks + half) ^ (l32 & 15);
            const short8 kf0 = *(const short8*)&KsU[l32 * CH + ph * 8];
            const short8 kf1 = *(const short8*)&KsU[(32 + l32) * CH + ph * 8];
            s0 = __builtin_amdgcn_mfma_f32_32x32x16_bf16(qa[ks], kf0, s0, 0, 0, 0);
            s1 = __builtin_amdgcn_mfma_f32_32x32x16_bf16(qa[ks], kf1, s1, 0, 0, 0);
        }

        // --- P = exp2(S) (m fixed) -> per-wave LDS scratch, row-major ---
        // (no fence: DS ops are wave-ordered; same-array alias keeps prog order)
        #pragma unroll
        for (int reg = 0; reg < 16; ++reg) {
            const int row = (reg & 3) + 8 * (reg >> 2) + 4 * half;
            Pw[row * PSTR + l32]      = f2bf(exp2f(s0[reg]));
            Pw[row * PSTR + 32 + l32] = f2bf(exp2f(s1[reg]));
        }

        // --- O += P V ; l += P * ones (no rescale: m is fixed) ---
        #pragma unroll
        for (int ks2 = 0; ks2 < 4; ++ks2) {
            const short8 pa = *(const short8*)&Pw[l32 * PSTR + ks2 * 16 + half * 8];
            #pragma unroll
            for (int ct = 0; ct < 4; ++ct) {
                const int ch = ct * 32 + l32;
                const int ph = (2 * ks2 + half) ^ (ch & 7);
                const short8 vf = *(const short8*)&VtU[ch * TK + ph * 8];
                Oa[ct] = __builtin_amdgcn_mfma_f32_32x32x16_bf16(pa, vf, Oa[ct], 0, 0, 0);
            }
            La = __builtin_amdgcn_mfma_f32_32x32x16_bf16(pa, ones8, La, 0, 0, 0);
        }
    }

    if constexpr (SPLIT == 1) {
        #pragma unroll
        for (int reg = 0; reg < 16; ++reg) {
            const int row = (reg & 3) + 8 * (reg >> 2) + 4 * half;
            const int n = n0 + 32 * w + row;
            const float inv = 1.0f / La[reg];
            #pragma unroll
            for (int ct = 0; ct < 4; ++ct)
                out[((size_t)b * CH + ct * 32 + l32) * NTOK + n] = Oa[ct][reg] * inv;
        }
    } else {
        const size_t chunk = (size_t)(b * SPLIT + jc);
        #pragma unroll
        for (int reg = 0; reg < 16; ++reg) {
            const int row = (reg & 3) + 8 * (reg >> 2) + 4 * half;
            const int n = n0 + 32 * w + row;
            const size_t base = (chunk * NTOK + n) * CH;
            #pragma unroll
            for (int ct = 0; ct < 4; ++ct)   // 64 B contiguous per 32 lanes
                Op[base + ct * 32 + l32] = f2bf(Oa[ct][reg]);
            if (l32 == 0) l_p[chunk * NTOK + n] = La[reg];
        }
    }
}

// ---------------- combine partials (plain sums; fixed m) ----------------
template <int SPLIT>
__global__ __launch_bounds__(256) void combine_kernel(
    const unsigned short* __restrict__ Op, const float* __restrict__ l_p,
    float* __restrict__ out)
{
    const int t  = threadIdx.x;
    const int cg = t & 31;
    const int r8 = t >> 5;
    const int n0 = blockIdx.x * 32;
    const int b  = blockIdx.y;

    for (int it = 0; it < 4; ++it) {
        const int n = n0 + it * 8 + r8;
        float den = 0.f;
        float acc[4] = {0.f, 0.f, 0.f, 0.f};
        #pragma unroll
        for (int j = 0; j < SPLIT; ++j) {
            const size_t chunk = (size_t)(b * SPLIT + j);
            den += l_p[chunk * NTOK + n];
            unsigned short o4[4];
            *(uint2*)o4 = *(const uint2*)&Op[(chunk * NTOK + n) * CH + cg * 4];
            #pragma unroll
            for (int e = 0; e < 4; ++e) acc[e] += bf2f(o4[e]);
        }
        const float inv = 1.0f / den;
        #pragma unroll
        for (int e = 0; e < 4; ++e)
            out[((size_t)b * CH + cg * 4 + e) * NTOK + n] = acc[e] * inv;
    }
}

extern "C" void kernel_launch(void* const* d_in, const int* in_sizes, int n_in,
                              void* d_out, int out_size, void* d_ws, size_t ws_size,
                              hipStream_t stream) {
    const float* x  = (const float*)d_in[0];
    const float* Wq = (const float*)d_in[1];
    const float* bq = (const float*)d_in[2];
    const float* Wk = (const float*)d_in[3];
    const float* bk = (const float*)d_in[4];
    const float* Wv = (const float*)d_in[5];
    const float* bv = (const float*)d_in[6];
    float* out = (float*)d_out;

    const size_t QKV = (size_t)BATCH * NTOK * CH;
    unsigned short* q_ws  = (unsigned short*)d_ws;
    unsigned short* k_ws  = q_ws + QKV;
    unsigned short* vt_ws = k_ws + QKV;
    unsigned short* Op    = vt_ws + QKV;   // bf16 partials [S*B][N][C]

    const size_t baseBytes = 3 * QKV * 2;
    auto needBytes = [&](size_t S) {
        return baseBytes + S * BATCH * NTOK * (size_t)(CH * 2 + 4);
    };

    dim3 gp(NTOK / 256, CH / 4, BATCH);
    proj_valu_kernel<<<gp, 256, 0, stream>>>(x, Wq, bq, Wk, bk, Wv, bv,
                                             q_ws, k_ws, vt_ws);

    if (ws_size >= needBytes(8)) {
        float* l_p = (float*)(Op + (size_t)8 * BATCH * NTOK * CH);
        dim3 ga(512, 1, 1);   // flat grid, XCD-swizzled decode in-kernel
        flash_attn_mfma<8><<<ga, 512, 0, stream>>>(q_ws, k_ws, vt_ws, out, Op, l_p);
        dim3 gc(NTOK / 32, BATCH);
        combine_kernel<8><<<gc, 256, 0, stream>>>(Op, l_p, out);
    } else if (ws_size >= needBytes(4)) {
        float* l_p = (float*)(Op + (size_t)4 * BATCH * NTOK * CH);
        dim3 ga(NTOK / QTILE, 4, BATCH);
        flash_attn_mfma<4><<<ga, 512, 0, stream>>>(q_ws, k_ws, vt_ws, out, Op, l_p);
        dim3 gc(NTOK / 32, BATCH);
        combine_kernel<4><<<gc, 256, 0, stream>>>(Op, l_p, out);
    } else {
        dim3 ga(NTOK / QTILE, 1, BATCH);
        flash_attn_mfma<1><<<ga, 512, 0, stream>>>(q_ws, k_ws, vt_ws, out,
                                                   nullptr, nullptr);
    }
}